// Round 10
// baseline (4918.093 us; speedup 1.0000x reference)
//
#include <hip/hip_runtime.h>

// VaeRNNDecoder: 512-step LSTM with output feedback, B=256, H=512.
// Folded recurrence: gates_t = h_t @ W_eff^T + b_eff,  W_eff = W_ih@W_last + W_hh.
// ROUND 10: r4 exchange protocol VERBATIM (8 groups x 16 pair-blocks,
// fetch_add + tid0-spin rendezvous, sc0sc1 stage loads, syncthreads drains)
// with ONE structural change: WAVE-LOCAL GATES. Each wave computes all five
// tiles {i,f,g,o,y} for one (slice, M-tile). MFMA C-layout (col=lane&15,
// row=q4*4+reg) puts i,f,g,o for a (batch,col) cell in the SAME lane/reg ->
// cell state c lives in 4 VGPRs/lane, gatesL+cL LDS buffers and the
// MFMA->cell barrier are eliminated. y-stores move after the wake barrier
// (HBM ack hides under next stage RTT; pre-publish drain waits LLC h only).
// Cost: bfrag[5][16] = 320 regs/lane (256 AGPR + 64 VGPR), est total ~400
// < 450 no-spill bound.
// Ledger: r1/r2 sc0-only BROKEN. r3 wide polling floods LLC. r4=1755us best.
// r5/r6 tick pipeline 2x worse. r7 bundling uninterpretable. r8 flag-line
// 1877. r9 atomic-swap publish 1814, WRITE_SIZE unchanged (write-through
// theory falsified). Exchange-protocol micro-levers are exhausted; this
// round attacks intra-block dataflow.

#define HH 512
#define TT 512

typedef _Float16 half8 __attribute__((ext_vector_type(8)));
typedef float f32x4 __attribute__((ext_vector_type(4)));

__device__ __forceinline__ float sigm(float x) { return 1.0f / (1.0f + __expf(-x)); }
__device__ __forceinline__ float tanh_(float x) { return 1.0f - 2.0f / (__expf(2.0f * x) + 1.0f); }
__device__ __forceinline__ unsigned short f16b(float x) {
    _Float16 h = (_Float16)x;
    return __builtin_bit_cast(unsigned short, h);
}

// ---------------- K1: W_eff gate rows -> Wbig (packed, f16) ----------------
__global__ __launch_bounds__(256) void k_weff(const float* __restrict__ Wih,
                                              const float* __restrict__ Whh,
                                              const float* __restrict__ Wlast,
                                              unsigned short* __restrict__ Wbig) {
    __shared__ float wih[16 * 512];
    const int tid = threadIdx.x;
    const int r0 = blockIdx.x * 16;
    for (int i = tid; i < (16 * 512) / 4; i += 256) {
        ((float4*)wih)[i] = ((const float4*)(Wih + (size_t)r0 * 512))[i];
    }
    __syncthreads();
    float acc0[16], acc1[16];
#pragma unroll
    for (int rr = 0; rr < 16; ++rr) { acc0[rr] = 0.f; acc1[rr] = 0.f; }
    const int k0 = tid * 2;
    for (int j = 0; j < 512; ++j) {
        const float2 wl = *(const float2*)(Wlast + (size_t)j * 512 + k0);
#pragma unroll
        for (int rr = 0; rr < 16; ++rr) {
            const float a = wih[rr * 512 + j];
            acc0[rr] += a * wl.x;
            acc1[rr] += a * wl.y;
        }
    }
#pragma unroll
    for (int rr = 0; rr < 16; ++rr) {
        const int gr = r0 + rr;
        const int q = gr >> 9, j = gr & 511;
        const int dst = 80 * (j >> 4) + q * 16 + (j & 15);
        const float v0 = acc0[rr] + Whh[(size_t)gr * 512 + k0];
        const float v1 = acc1[rr] + Whh[(size_t)gr * 512 + k0 + 1];
        Wbig[(size_t)dst * 512 + k0] = f16b(v0);
        Wbig[(size_t)dst * 512 + k0 + 1] = f16b(v1);
    }
}

// ---------------- K2: pack W0big, y-rows, biases, hbuf init, counters ------
__global__ __launch_bounds__(256) void k_pack(const float* __restrict__ z,
                                              const float* __restrict__ Wih,
                                              const float* __restrict__ Whh,
                                              const float* __restrict__ bih,
                                              const float* __restrict__ bhh,
                                              const float* __restrict__ Wlast,
                                              const float* __restrict__ blast,
                                              unsigned short* __restrict__ Wbig,
                                              unsigned short* __restrict__ W0big,
                                              float* __restrict__ biasEff,
                                              float* __restrict__ bias0,
                                              unsigned short* __restrict__ hbuf,
                                              unsigned int* __restrict__ counters) {
    const int nthr = gridDim.x * blockDim.x;
    const int gtid = blockIdx.x * blockDim.x + threadIdx.x;
    for (int e = gtid; e < 2560 * 512; e += nthr) {
        const int r = e >> 9, k = e & 511;
        const int s = r / 80, rem = r - s * 80;
        const int tau = rem >> 4, jj = rem & 15;
        const int j = s * 16 + jj;
        if (tau == 4) {
            const unsigned short v = f16b(Wlast[(size_t)j * 512 + k]);
            Wbig[e] = v;
            W0big[e] = v;
        } else {
            const int gr = tau * 512 + j;
            W0big[e] = f16b(Wih[(size_t)gr * 512 + k] + Whh[(size_t)gr * 512 + k]);
        }
    }
    for (int r = gtid; r < 2560; r += nthr) {
        const int s = r / 80, rem = r - s * 80;
        const int tau = rem >> 4, jj = rem & 15;
        const int j = s * 16 + jj;
        if (tau == 4) {
            bias0[r] = blast[j];
            biasEff[r] = blast[j];
        } else {
            const int gr = tau * 512 + j;
            const float base = bih[gr] + bhh[gr];
            float dot = 0.f;
            for (int k = 0; k < 512; ++k) dot += Wih[(size_t)gr * 512 + k] * blast[k];
            bias0[r] = base;
            biasEff[r] = base + dot;
        }
    }
    // hbuf: [g][parity][32 batch][512]; seed parity 0 with z
    for (int e = gtid; e < 256 * 512; e += nthr) {
        const int b = e >> 9, k = e & 511;
        const int g = b >> 5, bl = b & 31;
        hbuf[((size_t)(g * 2) * 32 + bl) * 512 + k] = f16b(z[e]);
    }
    for (int e = gtid; e < 512; e += nthr) counters[e] = 0u;
}

// ---------------- K3: persistent recurrence ----------------
// 128 blocks = 8 groups (blockIdx&7) x 16 pairs (blockIdx>>3). Pair-block
// owns slices {2p, 2p+1} = 160 packed rows. Wave w: slice = 2p + (w>>1),
// M-tile = w&1 (batches (w&1)*16..+15); computes tiles {i,f,g,o,y} for its
// (slice, M-tile) -> 80 MFMAs/wave, cell update wave-local, c in VGPRs.
__global__ __launch_bounds__(256, 1) void k_lstm(const unsigned short* __restrict__ Wbig,
                                                 const unsigned short* __restrict__ W0big,
                                                 const float* __restrict__ biasEff,
                                                 const float* __restrict__ bias0,
                                                 unsigned short* __restrict__ hbuf,
                                                 unsigned int* __restrict__ counters,
                                                 const float* __restrict__ z,
                                                 float* __restrict__ out) {
    const int g = blockIdx.x & 7;
    const int pair = blockIdx.x >> 3;
    const int tid = threadIdx.x;
    const int wave = tid >> 6;
    const int lane = tid & 63;
    const int l15 = lane & 15;
    const int q4 = lane >> 4;

    __shared__ unsigned short hstage[32 * 520];  // padded rows: stride 520 halves

    const int slice = 2 * pair + (wave >> 1);  // global slice id 0..31
    const int Mbase = (wave & 1) * 16;         // batch tile base
    const int jcol = 16 * slice + l15;         // this lane's hidden column

    unsigned short* hb0 = hbuf + (size_t)(g * 2) * 32 * 512;
    unsigned short* hb1 = hb0 + 32 * 512;
    unsigned int* cnt = counters + g * 64;

    // cell state: 4 cells/lane (batches Mbase+q4*4+r, column jcol), fp32 exact
    float c_reg[4];
#pragma unroll
    for (int r = 0; r < 4; ++r) {
        c_reg[r] = z[(size_t)(g * 32 + Mbase + q4 * 4 + r) * 512 + jcol];
    }

    // persistent B-fragments (fp16 weights), all 5 tiles, start with W0
    half8 bfrag[5][16];
#pragma unroll
    for (int tt = 0; tt < 5; ++tt) {
        const int row = 80 * slice + tt * 16 + l15;
#pragma unroll
        for (int kk = 0; kk < 16; ++kk) {
            bfrag[tt][kk] = *(const half8*)(W0big + (size_t)row * 512 + kk * 32 + q4 * 8);
        }
    }
    float bias0v[5], biasEv[5];
#pragma unroll
    for (int tt = 0; tt < 5; ++tt) {
        const int r = 80 * slice + tt * 16 + l15;
        bias0v[tt] = bias0[r];
        biasEv[tt] = biasEff[r];
    }

    for (int t = 0; t <= 512; ++t) {
        // ---- stage h(t): coherent LLC loads (sc0 sc1), one wait ----
        // The vmcnt(0) also drains the previous step's y-stores (issued just
        // before these loads -> HBM ack hides under the stage RTT).
        // NOTE: outputs MUST be early-clobber (=&v).
        {
            const unsigned short* src = (t & 1) ? hb1 : hb0;
            const char* p = (const char*)src + tid * 16;
            half8 st[8];
            asm volatile(
                "global_load_dwordx4 %0, %8, off sc0 sc1\n\t"
                "global_load_dwordx4 %1, %9, off sc0 sc1\n\t"
                "global_load_dwordx4 %2, %10, off sc0 sc1\n\t"
                "global_load_dwordx4 %3, %11, off sc0 sc1\n\t"
                "global_load_dwordx4 %4, %12, off sc0 sc1\n\t"
                "global_load_dwordx4 %5, %13, off sc0 sc1\n\t"
                "global_load_dwordx4 %6, %14, off sc0 sc1\n\t"
                "global_load_dwordx4 %7, %15, off sc0 sc1\n\t"
                "s_waitcnt vmcnt(0)"
                : "=&v"(st[0]), "=&v"(st[1]), "=&v"(st[2]), "=&v"(st[3]),
                  "=&v"(st[4]), "=&v"(st[5]), "=&v"(st[6]), "=&v"(st[7])
                : "v"(p), "v"(p + 4096), "v"(p + 8192), "v"(p + 12288),
                  "v"(p + 16384), "v"(p + 20480), "v"(p + 24576), "v"(p + 28672)
                : "memory");
#pragma unroll
            for (int i = 0; i < 8; ++i) {
                const int ci = i * 256 + tid;  // 16B chunk index, 0..2047
                const int row = ci >> 6, col = ci & 63;
                *(half8*)(hstage + row * 520 + col * 8) = st[i];
            }
        }
        __syncthreads();

        // ---- MFMA: 5 tiles {i,f,g,o,y} x 16 kk for (slice, M-tile) ----
        f32x4 acc[5];
#pragma unroll
        for (int tt = 0; tt < 5; ++tt) {
            const float bv = (t == 0) ? bias0v[tt] : biasEv[tt];
            acc[tt] = (f32x4){bv, bv, bv, bv};
        }
#pragma unroll
        for (int kk = 0; kk < 16; ++kk) {
            const half8 a = *(const half8*)(hstage + (Mbase + l15) * 520 + kk * 32 + q4 * 8);
#pragma unroll
            for (int tt = 0; tt < 5; ++tt) {
                acc[tt] = __builtin_amdgcn_mfma_f32_16x16x32_f16(a, bfrag[tt][kk], acc[tt], 0, 0, 0);
            }
        }

        if (t == 512) {
            // final y_{511} and done
#pragma unroll
            for (int r = 0; r < 4; ++r) {
                const size_t off = (size_t)(g * 32 + Mbase + q4 * 4 + r) * (TT * HH) +
                                   (size_t)(t - 1) * HH + jcol;
                out[off] = acc[4][r];
            }
            break;
        }

        // ---- cell update: WAVE-LOCAL. i,f,g,o for (batch,col) are in this
        // lane's acc[0..3][r]; c in c_reg[r]. h(t+1) -> sc0sc1 short stores.
        {
            unsigned short* dst = (t & 1) ? hb0 : hb1;  // parity (t+1)&1
#pragma unroll
            for (int r = 0; r < 4; ++r) {
                const float iv = acc[0][r], fv = acc[1][r], gv = acc[2][r], ov = acc[3][r];
                const float c0 = sigm(fv) * c_reg[r] + sigm(iv) * tanh_(gv);
                c_reg[r] = c0;
                const float h0 = sigm(ov) * tanh_(c0);
                unsigned short* pp = dst + (size_t)(Mbase + q4 * 4 + r) * 512 + jcol;
                const unsigned short hv = f16b(h0);
                asm volatile("global_store_short %0, %1, off sc0 sc1" ::"v"(pp), "v"(hv)
                             : "memory");
            }
        }

        // after step 0, swap persistent weights W0 -> W_eff (tiles 0..3 only;
        // tile 4 (y=Wlast) is identical in both). Loads drained by the
        // pre-publish __syncthreads below.
        if (t == 0) {
#pragma unroll
            for (int tt = 0; tt < 4; ++tt) {
                const int row = 80 * slice + tt * 16 + l15;
#pragma unroll
                for (int kk = 0; kk < 16; ++kk) {
                    bfrag[tt][kk] = *(const half8*)(Wbig + (size_t)row * 512 + kk * 32 + q4 * 8);
                }
            }
        }

        // ---- group barrier: relaxed agent counter, narrow tid0 spin ----
        // __syncthreads drains every thread's h stores (vmcnt ack at LLC for
        // sc1 stores) before tid0 arrives — the baseline-proven release.
        __syncthreads();
        if (tid == 0) {
            __hip_atomic_fetch_add(cnt, 1u, __ATOMIC_RELAXED, __HIP_MEMORY_SCOPE_AGENT);
            const unsigned int target = 16u * (unsigned)(t + 1);
            int guard = 0;
            while (__hip_atomic_load(cnt, __ATOMIC_RELAXED, __HIP_MEMORY_SCOPE_AGENT) < target &&
                   ++guard < 65536) {
            }
        }
        __syncthreads();

        // ---- y_{t-1} (t>=1): issued AFTER the wake; HBM ack hides under the
        // next stage's vmcnt(0) (~900cy of load RTT + LDS write).
        if (t >= 1) {
#pragma unroll
            for (int r = 0; r < 4; ++r) {
                const size_t off = (size_t)(g * 32 + Mbase + q4 * 4 + r) * (TT * HH) +
                                   (size_t)(t - 1) * HH + jcol;
                out[off] = acc[4][r];
            }
        }
    }
}

// ---------------- launch ----------------
extern "C" void kernel_launch(void* const* d_in, const int* in_sizes, int n_in,
                              void* d_out, int out_size, void* d_ws, size_t ws_size,
                              hipStream_t stream) {
    const float* z = (const float*)d_in[0];
    const float* Wih = (const float*)d_in[1];
    const float* Whh = (const float*)d_in[2];
    const float* bih = (const float*)d_in[3];
    const float* bhh = (const float*)d_in[4];
    const float* Wlast = (const float*)d_in[5];
    const float* blast = (const float*)d_in[6];
    float* out = (float*)d_out;

    char* ws = (char*)d_ws;
    unsigned short* Wbig = (unsigned short*)(ws);                // 2,621,440 B
    unsigned short* W0big = (unsigned short*)(ws + 2621440);     // 2,621,440 B
    float* biasEff = (float*)(ws + 5242880);                     // 10,240 B
    float* bias0 = (float*)(ws + 5253120);                       // 10,240 B
    unsigned short* hbuf = (unsigned short*)(ws + 5263360);      // 524,288 B
    unsigned int* counters = (unsigned int*)(ws + 5787648);      // 2,048 B

    k_weff<<<128, 256, 0, stream>>>(Wih, Whh, Wlast, Wbig);
    k_pack<<<512, 256, 0, stream>>>(z, Wih, Whh, bih, bhh, Wlast, blast, Wbig, W0big, biasEff,
                                    bias0, hbuf, counters);
    k_lstm<<<128, 256, 0, stream>>>(Wbig, W0big, biasEff, bias0, hbuf, counters, z, out);
}

// Round 11
// 2026.383 us; speedup vs baseline: 2.4270x; 2.4270x over previous
//
#include <hip/hip_runtime.h>

// VaeRNNDecoder: 512-step LSTM with output feedback, B=256, H=512.
// Folded recurrence: gates_t = h_t @ W_eff^T + b_eff,  W_eff = W_ih@W_last + W_hh.
// ROUND 11: r4 protocol VERBATIM, ONE structural change: 16 groups x 16
// batches (vs 8 x 32). Grid 256 blocks = full chip (r4 idled half the CUs).
// Same 4 MB/step broadcast (16 groups x 16 blocks x 16KB), same 16-wide
// rendezvous, same bfrag[3][16] (192 regs, proven no-spill), but per-block
// stage volume, critical-wave MFMA count, cell VALU and h-store count all
// halve. Exchange = baseline-proven: sc0sc1 stage loads, relaxed-agent h
// stores drained by __syncthreads vmcnt(0), fetch_add + tid0 narrow spin.
// Ledger: r1/r2 sc0-only BROKEN. r3 wide polling floods LLC. r4=1755us.
// r5/r6 tick pipeline 2x worse (rendezvous count doubles). r7 bundling
// uninterpretable. r8 flag-line 1877 (rendezvous primitive not the lever).
// r9 atomic-swap 1814, WRITE_SIZE unchanged (write-through theory false).
// r10 wave-local gates: bfrag[5] spills (VGPR cap 256, +1.2GB scratch
// traffic, 4710us) — weight-resident budget is ~192 regs / 3 tiles.

#define HH 512
#define TT 512

typedef _Float16 half8 __attribute__((ext_vector_type(8)));
typedef float f32x4 __attribute__((ext_vector_type(4)));

__device__ __forceinline__ float sigm(float x) { return 1.0f / (1.0f + __expf(-x)); }
__device__ __forceinline__ float tanh_(float x) { return 1.0f - 2.0f / (__expf(2.0f * x) + 1.0f); }
__device__ __forceinline__ unsigned short f16b(float x) {
    _Float16 h = (_Float16)x;
    return __builtin_bit_cast(unsigned short, h);
}

// ---------------- K1: W_eff gate rows -> Wbig (packed, f16) ----------------
__global__ __launch_bounds__(256) void k_weff(const float* __restrict__ Wih,
                                              const float* __restrict__ Whh,
                                              const float* __restrict__ Wlast,
                                              unsigned short* __restrict__ Wbig) {
    __shared__ float wih[16 * 512];
    const int tid = threadIdx.x;
    const int r0 = blockIdx.x * 16;
    for (int i = tid; i < (16 * 512) / 4; i += 256) {
        ((float4*)wih)[i] = ((const float4*)(Wih + (size_t)r0 * 512))[i];
    }
    __syncthreads();
    float acc0[16], acc1[16];
#pragma unroll
    for (int rr = 0; rr < 16; ++rr) { acc0[rr] = 0.f; acc1[rr] = 0.f; }
    const int k0 = tid * 2;
    for (int j = 0; j < 512; ++j) {
        const float2 wl = *(const float2*)(Wlast + (size_t)j * 512 + k0);
#pragma unroll
        for (int rr = 0; rr < 16; ++rr) {
            const float a = wih[rr * 512 + j];
            acc0[rr] += a * wl.x;
            acc1[rr] += a * wl.y;
        }
    }
#pragma unroll
    for (int rr = 0; rr < 16; ++rr) {
        const int gr = r0 + rr;
        const int q = gr >> 9, j = gr & 511;
        const int dst = 80 * (j >> 4) + q * 16 + (j & 15);
        const float v0 = acc0[rr] + Whh[(size_t)gr * 512 + k0];
        const float v1 = acc1[rr] + Whh[(size_t)gr * 512 + k0 + 1];
        Wbig[(size_t)dst * 512 + k0] = f16b(v0);
        Wbig[(size_t)dst * 512 + k0 + 1] = f16b(v1);
    }
}

// ---------------- K2: pack W0big, y-rows, biases, hbuf init, counters ------
__global__ __launch_bounds__(256) void k_pack(const float* __restrict__ z,
                                              const float* __restrict__ Wih,
                                              const float* __restrict__ Whh,
                                              const float* __restrict__ bih,
                                              const float* __restrict__ bhh,
                                              const float* __restrict__ Wlast,
                                              const float* __restrict__ blast,
                                              unsigned short* __restrict__ Wbig,
                                              unsigned short* __restrict__ W0big,
                                              float* __restrict__ biasEff,
                                              float* __restrict__ bias0,
                                              unsigned short* __restrict__ hbuf,
                                              unsigned int* __restrict__ counters) {
    const int nthr = gridDim.x * blockDim.x;
    const int gtid = blockIdx.x * blockDim.x + threadIdx.x;
    for (int e = gtid; e < 2560 * 512; e += nthr) {
        const int r = e >> 9, k = e & 511;
        const int s = r / 80, rem = r - s * 80;
        const int tau = rem >> 4, jj = rem & 15;
        const int j = s * 16 + jj;
        if (tau == 4) {
            const unsigned short v = f16b(Wlast[(size_t)j * 512 + k]);
            Wbig[e] = v;
            W0big[e] = v;
        } else {
            const int gr = tau * 512 + j;
            W0big[e] = f16b(Wih[(size_t)gr * 512 + k] + Whh[(size_t)gr * 512 + k]);
        }
    }
    for (int r = gtid; r < 2560; r += nthr) {
        const int s = r / 80, rem = r - s * 80;
        const int tau = rem >> 4, jj = rem & 15;
        const int j = s * 16 + jj;
        if (tau == 4) {
            bias0[r] = blast[j];
            biasEff[r] = blast[j];
        } else {
            const int gr = tau * 512 + j;
            const float base = bih[gr] + bhh[gr];
            float dot = 0.f;
            for (int k = 0; k < 512; ++k) dot += Wih[(size_t)gr * 512 + k] * blast[k];
            bias0[r] = base;
            biasEff[r] = base + dot;
        }
    }
    // hbuf: [g(16)][parity][16 batch][512]; seed parity 0 with z
    for (int e = gtid; e < 256 * 512; e += nthr) {
        const int b = e >> 9, k = e & 511;
        const int g = b >> 4, bl = b & 15;
        hbuf[(size_t)g * 16384 + bl * 512 + k] = f16b(z[e]);
    }
    // counters: 16 groups x 128B spacing (32 dwords) = 512 dwords
    for (int e = gtid; e < 512; e += nthr) counters[e] = 0u;
}

// ---------------- K3: persistent recurrence ----------------
// 256 blocks = 16 groups (blockIdx&15, 16 batches each) x 16 pairs
// (blockIdx>>4). Pair-block owns hidden cols [32*pair, 32*pair+32) =
// slices {2p, 2p+1} = 160 packed rows. Waves: w0: sliceA x {i,f,g};
// w1: sliceA x {o,y}; w2: sliceB x {i,f,g}; w3: sliceB x {o,y};
// single 16-batch M-tile (the group's batches).
__global__ __launch_bounds__(256, 1) void k_lstm(const unsigned short* __restrict__ Wbig,
                                                 const unsigned short* __restrict__ W0big,
                                                 const float* __restrict__ biasEff,
                                                 const float* __restrict__ bias0,
                                                 unsigned short* __restrict__ hbuf,
                                                 unsigned int* __restrict__ counters,
                                                 const float* __restrict__ z,
                                                 float* __restrict__ out) {
    const int g = blockIdx.x & 15;
    const int pair = blockIdx.x >> 4;
    const int tid = threadIdx.x;
    const int wave = tid >> 6;
    const int lane = tid & 63;
    const int l15 = lane & 15;
    const int q4 = lane >> 4;

    __shared__ unsigned short hstage[16 * 520];  // 16 batches, stride 520 halves
    __shared__ float gatesL[2 * 16 * 68];        // [sl][b][i(16) f g o], stride 68
    __shared__ float cL[2 * 16 * 18];            // [sl][b][16 cells], stride 18

    const int sl = wave >> 1;            // which slice of the pair this wave serves
    const int slice = 2 * pair + sl;     // global slice id 0..31
    const int ntile0 = (wave & 1) ? 3 : 0;
    const int ntcount = (wave & 1) ? 2 : 3;

    unsigned short* hb0 = hbuf + (size_t)g * 16384;  // [16][512] halves
    unsigned short* hb1 = hb0 + 8192;
    unsigned int* cnt = counters + g * 32;

    // c init from z (fp32 exact): 512 cells (16 batches x 32 cols), 2/thread
    for (int idx = tid; idx < 512; idx += 256) {
        const int b = idx >> 5, j0 = idx & 31;  // j0 = local col 0..31
        const int s2 = j0 >> 4, jj = j0 & 15;
        cL[(s2 * 16 + b) * 18 + jj] = z[(size_t)(g * 16 + b) * 512 + 32 * pair + j0];
    }

    // persistent B-fragments (fp16 weights), start with W0
    half8 bfrag[3][16];
#pragma unroll
    for (int tt = 0; tt < 3; ++tt) {
        if (tt < ntcount) {
            const int row = 80 * slice + (ntile0 + tt) * 16 + l15;
#pragma unroll
            for (int kk = 0; kk < 16; ++kk) {
                bfrag[tt][kk] = *(const half8*)(W0big + (size_t)row * 512 + kk * 32 + q4 * 8);
            }
        }
    }
    float bias0v[3], biasEv[3];
#pragma unroll
    for (int tt = 0; tt < 3; ++tt) {
        if (tt < ntcount) {
            const int r = 80 * slice + (ntile0 + tt) * 16 + l15;
            bias0v[tt] = bias0[r];
            biasEv[tt] = biasEff[r];
        } else {
            bias0v[tt] = 0.f;
            biasEv[tt] = 0.f;
        }
    }

    for (int t = 0; t <= 512; ++t) {
        // ---- stage h(t): 16KB coherent LLC loads (sc0 sc1), one wait ----
        // NOTE: outputs MUST be early-clobber (=&v): loads write dest regs while
        // later loads in the same asm block still need their address pairs.
        {
            const unsigned short* src = (t & 1) ? hb1 : hb0;
            const char* p = (const char*)src + tid * 16;
            half8 st[4];
            asm volatile(
                "global_load_dwordx4 %0, %4, off sc0 sc1\n\t"
                "global_load_dwordx4 %1, %5, off sc0 sc1\n\t"
                "global_load_dwordx4 %2, %6, off sc0 sc1\n\t"
                "global_load_dwordx4 %3, %7, off sc0 sc1\n\t"
                "s_waitcnt vmcnt(0)"
                : "=&v"(st[0]), "=&v"(st[1]), "=&v"(st[2]), "=&v"(st[3])
                : "v"(p), "v"(p + 4096), "v"(p + 8192), "v"(p + 12288)
                : "memory");
#pragma unroll
            for (int i = 0; i < 4; ++i) {
                const int ci = i * 256 + tid;  // 16B chunk index, 0..1023
                const int row = ci >> 6, col = ci & 63;
                *(half8*)(hstage + row * 520 + col * 8) = st[i];
            }
        }
        __syncthreads();

        // ---- MFMA: [gates | y] = h @ Wbig_pair^T + bias, one M-tile ----
        f32x4 acc[3];
#pragma unroll
        for (int tt = 0; tt < 3; ++tt) {
            const float bv = (t == 0) ? bias0v[tt] : biasEv[tt];
            acc[tt] = (f32x4){bv, bv, bv, bv};
        }
#pragma unroll
        for (int kk = 0; kk < 16; ++kk) {
            const half8 a = *(const half8*)(hstage + l15 * 520 + kk * 32 + q4 * 8);
#pragma unroll
            for (int tt = 0; tt < 3; ++tt) {
                if (tt < ntcount)
                    acc[tt] = __builtin_amdgcn_mfma_f32_16x16x32_f16(a, bfrag[tt][kk], acc[tt], 0, 0, 0);
            }
        }

        // ---- y_{t-1} output (waves 1/3 hold the y tile in acc[1]) ----
        if ((wave & 1) && t >= 1) {
            const int n = 16 * slice + l15;
#pragma unroll
            for (int r = 0; r < 4; ++r) {
                const int m = q4 * 4 + r;
                const size_t off =
                    (size_t)(g * 16 + m) * (TT * HH) + (size_t)(t - 1) * HH + n;
                out[off] = acc[1][r];
            }
        }
        if (t == 512) break;

        // ---- gate tiles -> LDS ----
        {
            const int nst = (wave & 1) ? 1 : 3;
#pragma unroll
            for (int tt = 0; tt < 3; ++tt) {
                if (tt < nst) {
                    const int col = (ntile0 + tt) * 16 + l15;
#pragma unroll
                    for (int r = 0; r < 4; ++r) {
                        const int m = q4 * 4 + r;
                        gatesL[(sl * 16 + m) * 68 + col] = acc[tt][r];
                    }
                }
            }
        }
        __syncthreads();

        // ---- cell update: 2 cells/thread; publish h(t+1) to LLC ----
        {
            const int b = tid >> 4, jp = tid & 15;
            const int j0 = jp * 2;               // local col 0..30 even
            const int s2 = j0 >> 4, jj = j0 & 15;
            const float* gb = gatesL + (s2 * 16 + b) * 68;
            const float2 iv = *(const float2*)(gb + jj);
            const float2 fvv = *(const float2*)(gb + 16 + jj);
            const float2 gv = *(const float2*)(gb + 32 + jj);
            const float2 ov = *(const float2*)(gb + 48 + jj);
            float* cp = cL + (s2 * 16 + b) * 18 + jj;
            float2 cv = *(const float2*)cp;
            const float c0 = sigm(fvv.x) * cv.x + sigm(iv.x) * tanh_(gv.x);
            const float c1 = sigm(fvv.y) * cv.y + sigm(iv.y) * tanh_(gv.y);
            const float h0 = sigm(ov.x) * tanh_(c0);
            const float h1 = sigm(ov.y) * tanh_(c1);
            cv.x = c0;
            cv.y = c1;
            *(float2*)cp = cv;
            unsigned short* dst = (t & 1) ? hb0 : hb1;  // parity (t+1)&1
            const unsigned int packed = (unsigned int)f16b(h0) | ((unsigned int)f16b(h1) << 16);
            __hip_atomic_store((unsigned int*)(dst + b * 512 + 32 * pair + j0), packed,
                               __ATOMIC_RELAXED, __HIP_MEMORY_SCOPE_AGENT);
        }

        // after step 0, swap persistent weights W0 -> W_eff (overlaps barrier)
        if (t == 0) {
#pragma unroll
            for (int tt = 0; tt < 3; ++tt) {
                if (tt < ntcount) {
                    const int row = 80 * slice + (ntile0 + tt) * 16 + l15;
#pragma unroll
                    for (int kk = 0; kk < 16; ++kk) {
                        bfrag[tt][kk] = *(const half8*)(Wbig + (size_t)row * 512 + kk * 32 + q4 * 8);
                    }
                }
            }
        }

        // ---- group barrier: relaxed agent counter, narrow tid0 spin ----
        // __syncthreads drains every thread's h stores (vmcnt ack at LLC)
        // before tid0 arrives, so readers polling the counter and then loading
        // with sc0 sc1 observe the new h values (baseline-proven release).
        __syncthreads();
        if (tid == 0) {
            __hip_atomic_fetch_add(cnt, 1u, __ATOMIC_RELAXED, __HIP_MEMORY_SCOPE_AGENT);
            const unsigned int target = 16u * (unsigned)(t + 1);
            int guard = 0;
            while (__hip_atomic_load(cnt, __ATOMIC_RELAXED, __HIP_MEMORY_SCOPE_AGENT) < target &&
                   ++guard < 65536) {
            }
        }
        __syncthreads();
    }
}

// ---------------- launch ----------------
extern "C" void kernel_launch(void* const* d_in, const int* in_sizes, int n_in,
                              void* d_out, int out_size, void* d_ws, size_t ws_size,
                              hipStream_t stream) {
    const float* z = (const float*)d_in[0];
    const float* Wih = (const float*)d_in[1];
    const float* Whh = (const float*)d_in[2];
    const float* bih = (const float*)d_in[3];
    const float* bhh = (const float*)d_in[4];
    const float* Wlast = (const float*)d_in[5];
    const float* blast = (const float*)d_in[6];
    float* out = (float*)d_out;

    char* ws = (char*)d_ws;
    unsigned short* Wbig = (unsigned short*)(ws);                // 2,621,440 B
    unsigned short* W0big = (unsigned short*)(ws + 2621440);     // 2,621,440 B
    float* biasEff = (float*)(ws + 5242880);                     // 10,240 B
    float* bias0 = (float*)(ws + 5253120);                       // 10,240 B
    unsigned short* hbuf = (unsigned short*)(ws + 5263360);      // 524,288 B
    unsigned int* counters = (unsigned int*)(ws + 5787648);      // 2,048 B

    k_weff<<<128, 256, 0, stream>>>(Wih, Whh, Wlast, Wbig);
    k_pack<<<512, 256, 0, stream>>>(z, Wih, Whh, bih, bhh, Wlast, blast, Wbig, W0big, biasEff,
                                    bias0, hbuf, counters);
    k_lstm<<<256, 256, 0, stream>>>(Wbig, W0big, biasEff, bias0, hbuf, counters, z, out);
}